// Round 2
// baseline (965.036 us; speedup 1.0000x reference)
//
#include <hip/hip_runtime.h>

typedef __attribute__((ext_vector_type(8))) short v8s;   // 8 x bf16 (x32 MFMA A/B frag)
typedef __attribute__((ext_vector_type(4))) short v4s;   // 4 x bf16 (x16 MFMA A/B frag)
typedef __attribute__((ext_vector_type(4))) float v4f;   // MFMA C/D frag
typedef unsigned short u16;
typedef unsigned int u32;

#define NRES 384
#define NN (NRES*NRES)          // 147456
#define QKVE (NN*128)           // 18874368 elems per bf16 buffer

__device__ __forceinline__ u16 f2b(float f){
  u32 u = __builtin_bit_cast(u32, f);
  u += 0x7FFFu + ((u>>16)&1u);          // RNE
  return (u16)(u>>16);
}
__device__ __forceinline__ float b2f(u16 h){
  u32 u = ((u32)h)<<16;
  return __builtin_bit_cast(float, u);
}
__device__ __forceinline__ int swz256(int row, int colb){  // 256B rows (128 bf16)
  return (row*256 + colb) ^ ((row&7)<<4);
}
__device__ __forceinline__ v4f mfma16(v4s a, v4s b, v4f c){
#if __has_builtin(__builtin_amdgcn_mfma_f32_16x16x16bf16_1k)
  return __builtin_amdgcn_mfma_f32_16x16x16bf16_1k(a, b, c, 0, 0, 0);
#else
  v4f d;
  asm("v_mfma_f32_16x16x16_bf16 %0, %1, %2, %3" : "=v"(d) : "v"(a), "v"(b), "v"(c));
  return d;
#endif
}

// ---------------- kernel 0: weight prep ----------------
// wts layout: 5 matrices of [128 n][128 k] bf16: 0=q(scaled),1=k,2=v,3=gate,4=o
__global__ __launch_bounds__(256) void k_prep_w(
    const float* __restrict__ qw, const float* __restrict__ kw,
    const float* __restrict__ vw, const float* __restrict__ gw,
    const float* __restrict__ ow, u16* __restrict__ wts){
  int gid = blockIdx.x*256 + threadIdx.x;    // 0..81919
  int m = gid >> 14, r = gid & 16383;
  int n = r >> 7, a = r & 127;
  const float* src = (m==0)?qw:((m==1)?kw:((m==2)?vw:((m==3)?gw:ow)));
  float v = src[a*128 + n];                  // all five are [a(=k)][n] row-major flat
  if (m==0) v *= 0.17677669529663687f;       // fold 1/sqrt(32) into q
  wts[gid] = f2b(v);
}

// ---------------- kernel 1: LN + q/k/gate/v projections + feat2d bias ----------------
// nbb layout (packed for attention's C-init loads): [h][k/4][q][k%4] bf16
__global__ __launch_bounds__(256) void k_ln_proj(
    const float* __restrict__ X, const float* __restrict__ lns,
    const float* __restrict__ lnb, const float* __restrict__ f2w,
    const float* __restrict__ gb, const u16* __restrict__ wts,
    u16* __restrict__ qbuf, u16* __restrict__ kbuf,
    u16* __restrict__ vT, u16* __restrict__ gbuf, u16* __restrict__ nbb){
  __shared__ __align__(16) u16 Xs[128*128];
  int tid = threadIdx.x;
  int blk = blockIdx.x;                      // 1152 tiles of 128 positions
  int p0 = blk*128;
  int bi = blk/3;                            // pair row i (= attention q for nbb)
  int j0 = (blk%3)*128;                      // pair col base (= attention key)

  { // stage 1: LayerNorm, 2 threads per position
    int row = tid>>1;
    int half = (tid&1)*64;
    const float4* xp4 = (const float4*)(X + (size_t)(p0+row)*128 + half);
    float4 v[16];
    float s=0.f, ss=0.f;
    #pragma unroll
    for (int i=0;i<16;i++){ v[i]=xp4[i];
      s  += v[i].x+v[i].y+v[i].z+v[i].w;
      ss += v[i].x*v[i].x+v[i].y*v[i].y+v[i].z*v[i].z+v[i].w*v[i].w; }
    s += __shfl_xor(s,1); ss += __shfl_xor(ss,1);
    float mu = s*(1.f/128.f);
    float rstd = rsqrtf(ss*(1.f/128.f) - mu*mu + 1e-5f);
    float nb0=0,nb1=0,nb2=0,nb3=0;
    #pragma unroll
    for (int i=0;i<16;i++){
      int c = half + i*4;
      float4 sc = *(const float4*)(lns+c);
      float4 bi4= *(const float4*)(lnb+c);
      float xn0 = (v[i].x-mu)*rstd*sc.x + bi4.x;
      float xn1 = (v[i].y-mu)*rstd*sc.y + bi4.y;
      float xn2 = (v[i].z-mu)*rstd*sc.z + bi4.z;
      float xn3 = (v[i].w-mu)*rstd*sc.w + bi4.w;
      float4 fw0 = *(const float4*)(f2w + (c+0)*4);
      float4 fw1 = *(const float4*)(f2w + (c+1)*4);
      float4 fw2 = *(const float4*)(f2w + (c+2)*4);
      float4 fw3 = *(const float4*)(f2w + (c+3)*4);
      nb0 += xn0*fw0.x + xn1*fw1.x + xn2*fw2.x + xn3*fw3.x;
      nb1 += xn0*fw0.y + xn1*fw1.y + xn2*fw2.y + xn3*fw3.y;
      nb2 += xn0*fw0.z + xn1*fw1.z + xn2*fw2.z + xn3*fw3.z;
      nb3 += xn0*fw0.w + xn1*fw1.w + xn2*fw2.w + xn3*fw3.w;
      u32 pk0 = (u32)f2b(xn0) | ((u32)f2b(xn1)<<16);
      u32 pk1 = (u32)f2b(xn2) | ((u32)f2b(xn3)<<16);
      *(u32*)((char*)Xs + swz256(row, c*2))   = pk0;
      *(u32*)((char*)Xs + swz256(row, c*2+4)) = pk1;
    }
    nb0 += __shfl_xor(nb0,1); nb1 += __shfl_xor(nb1,1);
    nb2 += __shfl_xor(nb2,1); nb3 += __shfl_xor(nb3,1);
    if ((tid&1)==0){
      int k = j0 + row;                       // key index
      int base2 = ((k>>2)*NRES + bi)*4 + (k&3);
      nbb[0*NN+base2]=f2b(nb0); nbb[1*NN+base2]=f2b(nb1);
      nbb[2*NN+base2]=f2b(nb2); nbb[3*NN+base2]=f2b(nb3);
    }
  }
  __syncthreads();

  // stage 2: four 128x128 GEMMs; each wave owns 32 output cols
  int wv = tid>>6, lane = tid&63, l15 = lane&15, lhi = lane>>4;
  const v4f z4 = {0.f,0.f,0.f,0.f};
  for (int mi=0; mi<4; mi++){
    int m = mi; if (mi==2) m=3; else if (mi==3) m=2;   // order q,k,gate,v (v last: reuses Xs)
    v4f acc[8][2];
    #pragma unroll
    for (int mf=0;mf<8;mf++){ acc[mf][0]=z4; acc[mf][1]=z4; }
    for (int ks=0; ks<4; ks++){
      v8s af[8];
      #pragma unroll
      for (int mf=0;mf<8;mf++)
        af[mf] = *(const v8s*)((char*)Xs + swz256(mf*16+l15, (ks*32+lhi*8)*2));
      v8s bf[2];
      #pragma unroll
      for (int nf=0;nf<2;nf++)
        bf[nf] = *(const v8s*)(wts + m*16384 + (wv*32+nf*16+l15)*128 + ks*32 + lhi*8);
      #pragma unroll
      for (int mf=0;mf<8;mf++){
        acc[mf][0] = __builtin_amdgcn_mfma_f32_16x16x32_bf16(af[mf], bf[0], acc[mf][0],0,0,0);
        acc[mf][1] = __builtin_amdgcn_mfma_f32_16x16x32_bf16(af[mf], bf[1], acc[mf][1],0,0,0);
      }
    }
    if (mi==3){        // v: transpose via LDS so vT[b][h][d][j] global writes coalesce
      __syncthreads();
      #pragma unroll
      for (int mf=0;mf<8;mf++)
        #pragma unroll
        for (int nf=0;nf<2;nf++)
          #pragma unroll
          for (int r=0;r<4;r++){
            int pr = mf*16 + lhi*4 + r;
            int n  = wv*32 + nf*16 + l15;
            *(u16*)((char*)Xs + swz256(n, pr*2)) = f2b(acc[mf][nf][r]);
          }
      __syncthreads();
      int n = tid>>1, jh = (tid&1)*64;
      int hh = n>>5, d = n&31;
      u16* dst = vT + (size_t)((bi*4+hh)*32 + d)*NRES + j0 + jh;
      #pragma unroll
      for (int i=0;i<32;i++){
        u32 val = *(u32*)((char*)Xs + swz256(n, (jh+i*2)*2));
        *(u32*)(dst + i*2) = val;
      }
    } else {
      u16* outp = (m==0)?qbuf:((m==1)?kbuf:gbuf);
      #pragma unroll
      for (int mf=0;mf<8;mf++)
        #pragma unroll
        for (int nf=0;nf<2;nf++){
          int n = wv*32 + nf*16 + l15;
          #pragma unroll
          for (int r=0;r<4;r++){
            int pr = mf*16 + lhi*4 + r;
            float val = acc[mf][nf][r];
            if (m==3) val = 1.f/(1.f+__expf(-(val + gb[n])));   // gate sigmoid
            outp[(size_t)(p0+pr)*128 + n] = f2b(val);
          }
        }
    }
  }
}

// ---------------- kernel 2: attention v2 (swapped QK^T, in-register P→PV) ----------------
// Wave task: 16 q-rows x 384 keys x 1 head; 4 waves x 4 heads per block.
// S^T frag layout: (key = mf*16+lhi*4+r, q = l15) -> exp'd frag IS the
// 16x16x16 PV A-frag (A[row=l15(q)][k=lhi*4+r]). No LDS P tile, no barriers.
__global__ __launch_bounds__(256,3) void k_attn(
    u16* qwg,                                  // q in, weighted*gate out (same buffer)
    const u16* __restrict__ kbuf, const u16* __restrict__ vT,
    const u16* __restrict__ gbuf, const u16* __restrict__ nbb,
    const float* __restrict__ mask){
  __shared__ float lmask[NRES];
  int tid = threadIdx.x;
  int bid = blockIdx.x;                        // 0..2303
  int xcd = bid & 7, li = bid >> 3;            // XCD-contiguous b chunks (2304 = 8*288)
  int t = xcd*288 + li;
  int b = t/6, qt = t - b*6;
  int q0 = qt*64;
  for (int i = tid; i < NRES; i += 256)
    lmask[i] = 1e9f*(mask[b*NRES + i] - 1.0f);
  __syncthreads();                             // only barrier in the kernel

  int wv = tid>>6, lane = tid&63, l15 = lane&15, lhi = lane>>4;
  int q0t = q0 + wv*16;
  const v4f z4 = {0.f,0.f,0.f,0.f};

  for (int h=0; h<4; h++){
    // Q B-frag: B[n=q=l15][c=lhi*8..+7]
    v8s qb = *(const v8s*)(qwg + (size_t)(b*NRES + q0t + l15)*128 + h*32 + lhi*8);
    v4f s[24];
    #pragma unroll
    for (int mf=0; mf<24; mf++){
      // bias as MFMA C-input: mask + nb_bias, element r <-> key mf*16+lhi*4+r
      v4s nb4 = *(const v4s*)(nbb + (size_t)h*NN + ((mf*4+lhi)*NRES + q0t + l15)*4);
      float4 mb4 = *(const float4*)&lmask[mf*16 + lhi*4];
      v4f c;
      c[0] = mb4.x + b2f((u16)nb4[0]);
      c[1] = mb4.y + b2f((u16)nb4[1]);
      c[2] = mb4.z + b2f((u16)nb4[2]);
      c[3] = mb4.w + b2f((u16)nb4[3]);
      // K A-frag: A[m=key=mf*16+l15][c=lhi*8..+7]
      v8s ka = *(const v8s*)(kbuf + (size_t)(b*NRES + mf*16 + l15)*128 + h*32 + lhi*8);
      s[mf] = __builtin_amdgcn_mfma_f32_16x16x32_bf16(ka, qb, c, 0,0,0);
    }
    // row max: in-lane (4 chains) + across lhi groups
    float m0=-1e30f, m1=-1e30f, m2=-1e30f, m3=-1e30f;
    #pragma unroll
    for (int mf=0; mf<24; mf++){
      m0 = fmaxf(m0, s[mf][0]); m1 = fmaxf(m1, s[mf][1]);
      m2 = fmaxf(m2, s[mf][2]); m3 = fmaxf(m3, s[mf][3]);
    }
    float mx = fmaxf(fmaxf(m0,m1), fmaxf(m2,m3));
    mx = fmaxf(mx, __shfl_xor(mx,16));
    mx = fmaxf(mx, __shfl_xor(mx,32));
    // exp + sum + PV fused (s[mf] dies per iteration; 4 indep MFMA chains)
    v4f oe0=z4, oe1=z4, oo0=z4, oo1=z4;
    float se=0.f, so=0.f;
    const u16* vbase = vT + (size_t)((b*4+h)*32)*NRES;
    #pragma unroll
    for (int mf=0; mf<24; mf++){
      float p0 = __expf(s[mf][0]-mx), p1 = __expf(s[mf][1]-mx);
      float p2 = __expf(s[mf][2]-mx), p3 = __expf(s[mf][3]-mx);
      v4s pa;
      pa[0]=(short)f2b(p0); pa[1]=(short)f2b(p1);
      pa[2]=(short)f2b(p2); pa[3]=(short)f2b(p3);
      // V B-frags (16x16x16): B[n=d][k=lhi*4..+3] from vT[d][key]
      v4s vb0 = *(const v4s*)(vbase + (size_t)(l15)*NRES      + mf*16 + lhi*4);
      v4s vb1 = *(const v4s*)(vbase + (size_t)(16+l15)*NRES   + mf*16 + lhi*4);
      if (mf & 1){
        so += (p0+p1)+(p2+p3);
        oo0 = mfma16(pa, vb0, oo0);
        oo1 = mfma16(pa, vb1, oo1);
      } else {
        se += (p0+p1)+(p2+p3);
        oe0 = mfma16(pa, vb0, oe0);
        oe1 = mfma16(pa, vb1, oe1);
      }
    }
    float sum = se + so;
    sum += __shfl_xor(sum,16); sum += __shfl_xor(sum,32);
    v4f o0 = oe0 + oo0, o1 = oe1 + oo1;        // (q=lhi*4+r, d=nf*16+l15)
    // normalize + gate + store
    #pragma unroll
    for (int r=0; r<4; r++){
      float rinv = 1.f/__shfl(sum, lhi*4+r);   // sum lives at lane l15=q
      size_t base = (size_t)(b*NRES + q0t + lhi*4 + r)*128 + h*32;
      float g0 = b2f(gbuf[base + l15]);
      float g1 = b2f(gbuf[base + 16 + l15]);
      qwg[base + l15]      = f2b(o0[r]*rinv*g0);
      qwg[base + 16 + l15] = f2b(o1[r]*rinv*g1);
    }
  }
}

// ---------------- kernel 3: output projection ----------------
__global__ __launch_bounds__(256) void k_outproj(
    const u16* __restrict__ wg, const u16* __restrict__ wts,
    const float* __restrict__ ob, float* __restrict__ out){
  int tid = threadIdx.x;
  int p0 = blockIdx.x*128;
  int wv = tid>>6, lane = tid&63, l15 = lane&15, lhi = lane>>4;
  const v4f z4 = {0.f,0.f,0.f,0.f};
  v4f acc[8][2];
  #pragma unroll
  for (int mf=0;mf<8;mf++){ acc[mf][0]=z4; acc[mf][1]=z4; }
  const u16* wo = wts + 4*16384;
  #pragma unroll
  for (int ks=0;ks<4;ks++){
    v8s af[8];
    #pragma unroll
    for (int mf=0;mf<8;mf++)
      af[mf] = *(const v8s*)(wg + (size_t)(p0+mf*16+l15)*128 + ks*32 + lhi*8);
    v8s bf[2];
    #pragma unroll
    for (int nf=0;nf<2;nf++)
      bf[nf] = *(const v8s*)(wo + (wv*32+nf*16+l15)*128 + ks*32 + lhi*8);
    #pragma unroll
    for (int mf=0;mf<8;mf++){
      acc[mf][0] = __builtin_amdgcn_mfma_f32_16x16x32_bf16(af[mf], bf[0], acc[mf][0],0,0,0);
      acc[mf][1] = __builtin_amdgcn_mfma_f32_16x16x32_bf16(af[mf], bf[1], acc[mf][1],0,0,0);
    }
  }
  #pragma unroll
  for (int nf=0;nf<2;nf++){
    int n = wv*32 + nf*16 + l15;
    float obn = ob[n];
    #pragma unroll
    for (int mf=0;mf<8;mf++)
      #pragma unroll
      for (int r=0;r<4;r++)
        out[(size_t)(p0+mf*16+lhi*4+r)*128 + n] = acc[mf][nf][r] + obn;
  }
}

extern "C" void kernel_launch(void* const* d_in, const int* in_sizes, int n_in,
                              void* d_out, int out_size, void* d_ws, size_t ws_size,
                              hipStream_t stream){
  const float* pair_act = (const float*)d_in[0];
  const float* pair_mask= (const float*)d_in[1];
  const float* ln_scale = (const float*)d_in[2];
  const float* ln_bias  = (const float*)d_in[3];
  const float* f2w      = (const float*)d_in[4];
  const float* q_w      = (const float*)d_in[5];
  const float* k_w      = (const float*)d_in[6];
  const float* v_w      = (const float*)d_in[7];
  const float* g_w      = (const float*)d_in[8];
  const float* g_b      = (const float*)d_in[9];
  const float* o_w      = (const float*)d_in[10];
  const float* o_b      = (const float*)d_in[11];
  float* out = (float*)d_out;

  u16* qbuf = (u16*)d_ws;                 // q, later weighted*gate
  u16* kbuf = qbuf + (size_t)QKVE;
  u16* vT   = kbuf + (size_t)QKVE;        // [b][h][d][j]
  u16* gbuf = vT   + (size_t)QKVE;        // sigmoid(gate)
  u16* nbb  = gbuf + (size_t)QKVE;        // [h][k/4][q][k%4] bf16 packed
  u16* wts  = nbb  + (size_t)(4*NN);      // 5 x 128x128 bf16

  hipLaunchKernelGGL(k_prep_w, dim3(320), dim3(256), 0, stream,
                     q_w, k_w, v_w, g_w, o_w, wts);
  hipLaunchKernelGGL(k_ln_proj, dim3(1152), dim3(256), 0, stream,
                     pair_act, ln_scale, ln_bias, f2w, g_b, wts,
                     qbuf, kbuf, vT, gbuf, nbb);
  hipLaunchKernelGGL(k_attn, dim3(2304), dim3(256), 0, stream,
                     qbuf, kbuf, vT, gbuf, nbb, pair_mask);
  hipLaunchKernelGGL(k_outproj, dim3(1152), dim3(256), 0, stream,
                     qbuf, wts, o_b, out);
}

// Round 5
// 769.905 us; speedup vs baseline: 1.2534x; 1.2534x over previous
//
#include <hip/hip_runtime.h>

typedef __attribute__((ext_vector_type(8))) short v8s;   // 8 x bf16 (x32 MFMA A/B frag)
typedef __attribute__((ext_vector_type(4))) short v4s;   // 4 x bf16 (x16 MFMA A/B frag)
typedef __attribute__((ext_vector_type(4))) float v4f;   // MFMA C/D frag
typedef unsigned short u16;
typedef unsigned int u32;

#define NRES 384
#define NN (NRES*NRES)          // 147456
#define QKVE (NN*128)           // 18874368 elems per bf16 buffer

__device__ __forceinline__ u16 f2b(float f){
  u32 u = __builtin_bit_cast(u32, f);
  u += 0x7FFFu + ((u>>16)&1u);          // RNE
  return (u16)(u>>16);
}
__device__ __forceinline__ float b2f(u16 h){
  u32 u = ((u32)h)<<16;
  return __builtin_bit_cast(float, u);
}
__device__ __forceinline__ int swz256(int row, int colb){  // 256B rows (128 bf16)
  return (row*256 + colb) ^ ((row&7)<<4);
}
__device__ __forceinline__ v4f mfma16(v4s a, v4s b, v4f c){
#if __has_builtin(__builtin_amdgcn_mfma_f32_16x16x16bf16_1k)
  return __builtin_amdgcn_mfma_f32_16x16x16bf16_1k(a, b, c, 0, 0, 0);
#else
  v4f d;
  asm("v_mfma_f32_16x16x16_bf16 %0, %1, %2, %3" : "=&v"(d) : "v"(a), "v"(b), "v"(c));
  return d;
#endif
}

// ---------------- kernel 0: weight prep ----------------
// wts layout: 5 matrices of [128 n][128 k] bf16: 0=q(scaled),1=k,2=v,3=gate,4=o
__global__ __launch_bounds__(256) void k_prep_w(
    const float* __restrict__ qw, const float* __restrict__ kw,
    const float* __restrict__ vw, const float* __restrict__ gw,
    const float* __restrict__ ow, u16* __restrict__ wts){
  int gid = blockIdx.x*256 + threadIdx.x;    // 0..81919
  int m = gid >> 14, r = gid & 16383;
  int n = r >> 7, a = r & 127;
  const float* src = (m==0)?qw:((m==1)?kw:((m==2)?vw:((m==3)?gw:ow)));
  float v = src[a*128 + n];                  // all five are [a(=k)][n] row-major flat
  if (m==0) v *= 0.17677669529663687f;       // fold 1/sqrt(32) into q
  wts[gid] = f2b(v);
}

// ---------------- kernel 1: LN + q/k/gate/v projections + feat2d bias ----------------
// nbb layout (packed for attention's C-init loads): [h][k/4][q][k%4] bf16
__global__ __launch_bounds__(256) void k_ln_proj(
    const float* __restrict__ X, const float* __restrict__ lns,
    const float* __restrict__ lnb, const float* __restrict__ f2w,
    const float* __restrict__ gb, const u16* __restrict__ wts,
    u16* __restrict__ qbuf, u16* __restrict__ kbuf,
    u16* __restrict__ vT, u16* __restrict__ gbuf, u16* __restrict__ nbb){
  __shared__ __align__(16) u16 Xs[128*128];
  int tid = threadIdx.x;
  int blk = blockIdx.x;                      // 1152 tiles of 128 positions
  int p0 = blk*128;
  int bi = blk/3;                            // pair row i (= attention q for nbb)
  int j0 = (blk%3)*128;                      // pair col base (= attention key)

  { // stage 1: LayerNorm, 2 threads per position
    int row = tid>>1;
    int half = (tid&1)*64;
    const float4* xp4 = (const float4*)(X + (size_t)(p0+row)*128 + half);
    float4 v[16];
    float s=0.f, ss=0.f;
    #pragma unroll
    for (int i=0;i<16;i++){ v[i]=xp4[i];
      s  += v[i].x+v[i].y+v[i].z+v[i].w;
      ss += v[i].x*v[i].x+v[i].y*v[i].y+v[i].z*v[i].z+v[i].w*v[i].w; }
    s += __shfl_xor(s,1); ss += __shfl_xor(ss,1);
    float mu = s*(1.f/128.f);
    float rstd = rsqrtf(ss*(1.f/128.f) - mu*mu + 1e-5f);
    float nb0=0,nb1=0,nb2=0,nb3=0;
    #pragma unroll
    for (int i=0;i<16;i++){
      int c = half + i*4;
      float4 sc = *(const float4*)(lns+c);
      float4 bi4= *(const float4*)(lnb+c);
      float xn0 = (v[i].x-mu)*rstd*sc.x + bi4.x;
      float xn1 = (v[i].y-mu)*rstd*sc.y + bi4.y;
      float xn2 = (v[i].z-mu)*rstd*sc.z + bi4.z;
      float xn3 = (v[i].w-mu)*rstd*sc.w + bi4.w;
      float4 fw0 = *(const float4*)(f2w + (c+0)*4);
      float4 fw1 = *(const float4*)(f2w + (c+1)*4);
      float4 fw2 = *(const float4*)(f2w + (c+2)*4);
      float4 fw3 = *(const float4*)(f2w + (c+3)*4);
      nb0 += xn0*fw0.x + xn1*fw1.x + xn2*fw2.x + xn3*fw3.x;
      nb1 += xn0*fw0.y + xn1*fw1.y + xn2*fw2.y + xn3*fw3.y;
      nb2 += xn0*fw0.z + xn1*fw1.z + xn2*fw2.z + xn3*fw3.z;
      nb3 += xn0*fw0.w + xn1*fw1.w + xn2*fw2.w + xn3*fw3.w;
      u32 pk0 = (u32)f2b(xn0) | ((u32)f2b(xn1)<<16);
      u32 pk1 = (u32)f2b(xn2) | ((u32)f2b(xn3)<<16);
      *(u32*)((char*)Xs + swz256(row, c*2))   = pk0;
      *(u32*)((char*)Xs + swz256(row, c*2+4)) = pk1;
    }
    nb0 += __shfl_xor(nb0,1); nb1 += __shfl_xor(nb1,1);
    nb2 += __shfl_xor(nb2,1); nb3 += __shfl_xor(nb3,1);
    if ((tid&1)==0){
      int k = j0 + row;                       // key index
      int base2 = ((k>>2)*NRES + bi)*4 + (k&3);
      nbb[0*NN+base2]=f2b(nb0); nbb[1*NN+base2]=f2b(nb1);
      nbb[2*NN+base2]=f2b(nb2); nbb[3*NN+base2]=f2b(nb3);
    }
  }
  __syncthreads();

  // stage 2: four 128x128 GEMMs; each wave owns 32 output cols
  int wv = tid>>6, lane = tid&63, l15 = lane&15, lhi = lane>>4;
  const v4f z4 = {0.f,0.f,0.f,0.f};
  for (int mi=0; mi<4; mi++){
    int m = mi; if (mi==2) m=3; else if (mi==3) m=2;   // order q,k,gate,v (v last: reuses Xs)
    v4f acc[8][2];
    #pragma unroll
    for (int mf=0;mf<8;mf++){ acc[mf][0]=z4; acc[mf][1]=z4; }
    for (int ks=0; ks<4; ks++){
      v8s af[8];
      #pragma unroll
      for (int mf=0;mf<8;mf++)
        af[mf] = *(const v8s*)((char*)Xs + swz256(mf*16+l15, (ks*32+lhi*8)*2));
      v8s bf[2];
      #pragma unroll
      for (int nf=0;nf<2;nf++)
        bf[nf] = *(const v8s*)(wts + m*16384 + (wv*32+nf*16+l15)*128 + ks*32 + lhi*8);
      #pragma unroll
      for (int mf=0;mf<8;mf++){
        acc[mf][0] = __builtin_amdgcn_mfma_f32_16x16x32_bf16(af[mf], bf[0], acc[mf][0],0,0,0);
        acc[mf][1] = __builtin_amdgcn_mfma_f32_16x16x32_bf16(af[mf], bf[1], acc[mf][1],0,0,0);
      }
    }
    if (mi==3){        // v: transpose via LDS so vT[b][h][d][j] global writes coalesce
      __syncthreads();
      #pragma unroll
      for (int mf=0;mf<8;mf++)
        #pragma unroll
        for (int nf=0;nf<2;nf++)
          #pragma unroll
          for (int r=0;r<4;r++){
            int pr = mf*16 + lhi*4 + r;
            int n  = wv*32 + nf*16 + l15;
            *(u16*)((char*)Xs + swz256(n, pr*2)) = f2b(acc[mf][nf][r]);
          }
      __syncthreads();
      int n = tid>>1, jh = (tid&1)*64;
      int hh = n>>5, d = n&31;
      u16* dst = vT + (size_t)((bi*4+hh)*32 + d)*NRES + j0 + jh;
      #pragma unroll
      for (int i=0;i<32;i++){
        u32 val = *(u32*)((char*)Xs + swz256(n, (jh+i*2)*2));
        *(u32*)(dst + i*2) = val;
      }
    } else {
      u16* outp = (m==0)?qbuf:((m==1)?kbuf:gbuf);
      #pragma unroll
      for (int mf=0;mf<8;mf++)
        #pragma unroll
        for (int nf=0;nf<2;nf++){
          int n = wv*32 + nf*16 + l15;
          #pragma unroll
          for (int r=0;r<4;r++){
            int pr = mf*16 + lhi*4 + r;
            float val = acc[mf][nf][r];
            if (m==3) val = 1.f/(1.f+__expf(-(val + gb[n])));   // gate sigmoid
            outp[(size_t)(p0+pr)*128 + n] = f2b(val);
          }
        }
    }
  }
}

// ---------------- kernel 2: attention v5 ----------------
// Block = (b, h). Stage K_h/V_h to LDS ONCE (plain reg-staged ds_write, no
// async, no rotation, no inline asm), one barrier, then 4 waves x 6 q-tiles
// fully independent. K_h LDS: [384 keys][80B] (64B data + 16B pad).
// V_h LDS: [32 d][784B] (768B data + 16B pad; row stride 49 chunks -> bank
// step 4 -> <=2 lanes/bank on 8B reads = conflict-free per m136).
__global__ __launch_bounds__(256,2) void k_attn(
    u16* qwg,                                  // q in, weighted*gate out (same buffer)
    const u16* __restrict__ kbuf, const u16* __restrict__ vT,
    const u16* __restrict__ gbuf, const u16* __restrict__ nbb,
    const float* __restrict__ mask){
  __shared__ __align__(16) char Ks[30720];     // 384*80
  __shared__ __align__(16) char Vs[25088];     // 32*784
  __shared__ __align__(16) float lmask[NRES];
  int tid = threadIdx.x, lane = tid&63, wv = tid>>6;
  int l15 = lane&15, lhi = lane>>4;
  int bid = blockIdx.x;                        // 1536 = 8 XCDs * 192
  int xcd = bid & 7, li = bid >> 3;
  int t = xcd*192 + li;
  int b = t>>2, h = t&3;                       // 4 heads of one b share an XCD's L2
  const v4f z4 = {0.f,0.f,0.f,0.f};

  for (int i = tid; i < NRES; i += 256)
    lmask[i] = 1e9f*(mask[b*NRES + i] - 1.0f);
  { // stage K: 1536 x 16B chunks, coalesced reads, conflict-free writes
    const u16* kb = kbuf + (size_t)b*NRES*128 + h*32;
    #pragma unroll
    for (int it=0; it<6; it++){
      int c2 = it*256 + tid;
      int key = c2>>2, j = c2&3;
      float4 d4 = *(const float4*)(kb + (size_t)key*128 + j*8);
      *(float4*)(Ks + key*80 + j*16) = d4;
    }
    // stage V: linear reads, padded-linear writes
    const u16* vb = vT + (size_t)(b*4+h)*32*NRES;
    #pragma unroll
    for (int it=0; it<6; it++){
      int c2 = it*256 + tid;
      int d = c2/48, cc = c2 - d*48;
      float4 d4 = *(const float4*)(vb + (size_t)d*NRES + cc*8);
      *(float4*)(Vs + d*784 + cc*16) = d4;
    }
  }
  __syncthreads();                             // only barrier in the kernel

  for (int qi=0; qi<6; qi++){
    int q0t = (wv*6 + qi)*16;
    // Q B-frag: B[n=q=l15][c=lhi*8..+7]
    v8s qb = *(const v8s*)(qwg + (size_t)(b*NRES + q0t + l15)*128 + h*32 + lhi*8);
    v4f s[24];
    #pragma unroll
    for (int mf=0; mf<24; mf++){
      // bias as MFMA C-input: mask + nb_bias, element r <-> key mf*16+lhi*4+r
      v4s nb4 = *(const v4s*)(nbb + (size_t)h*NN + ((size_t)(mf*4+lhi)*NRES + q0t + l15)*4);
      float4 mb4 = *(const float4*)&lmask[mf*16 + lhi*4];
      v4f c;
      c[0] = mb4.x + b2f((u16)nb4[0]);
      c[1] = mb4.y + b2f((u16)nb4[1]);
      c[2] = mb4.z + b2f((u16)nb4[2]);
      c[3] = mb4.w + b2f((u16)nb4[3]);
      // K A-frag from LDS: A[m=key=mf*16+l15][c=lhi*8..+7]
      v8s ka = *(const v8s*)(Ks + (mf*16+l15)*80 + lhi*16);
      s[mf] = __builtin_amdgcn_mfma_f32_16x16x32_bf16(ka, qb, c, 0,0,0);
    }
    // row max: in-lane (4 chains) + across lhi groups
    float m0=-1e30f, m1=-1e30f, m2=-1e30f, m3=-1e30f;
    #pragma unroll
    for (int mf=0; mf<24; mf++){
      m0 = fmaxf(m0, s[mf][0]); m1 = fmaxf(m1, s[mf][1]);
      m2 = fmaxf(m2, s[mf][2]); m3 = fmaxf(m3, s[mf][3]);
    }
    float mx = fmaxf(fmaxf(m0,m1), fmaxf(m2,m3));
    mx = fmaxf(mx, __shfl_xor(mx,16));
    mx = fmaxf(mx, __shfl_xor(mx,32));

    // exp + sum + PV fused; V B-frags from padded LDS
    v4f oe0=z4, oe1=z4, oo0=z4, oo1=z4;
    float se=0.f, so=0.f;
    #pragma unroll
    for (int mf=0; mf<24; mf++){
      float p0 = __expf(s[mf][0]-mx), p1 = __expf(s[mf][1]-mx);
      float p2 = __expf(s[mf][2]-mx), p3 = __expf(s[mf][3]-mx);
      v4s pa;
      pa[0]=(short)f2b(p0); pa[1]=(short)f2b(p1);
      pa[2]=(short)f2b(p2); pa[3]=(short)f2b(p3);
      // V[d][key]: byte = d*784 + (key u16)*2 ; key block = mf*16 + lhi*4
      int vo = mf*32 + lhi*8;                  // byte offset within row
      int d0 = l15, d1 = 16 + l15;
      v4s vb0 = *(const v4s*)(Vs + d0*784 + vo);
      v4s vb1 = *(const v4s*)(Vs + d1*784 + vo);
      if (mf & 1){
        so += (p0+p1)+(p2+p3);
        oo0 = mfma16(pa, vb0, oo0);
        oo1 = mfma16(pa, vb1, oo1);
      } else {
        se += (p0+p1)+(p2+p3);
        oe0 = mfma16(pa, vb0, oe0);
        oe1 = mfma16(pa, vb1, oe1);
      }
    }
    float sum = se + so;
    sum += __shfl_xor(sum,16); sum += __shfl_xor(sum,32);
    v4f o0 = oe0 + oo0, o1 = oe1 + oo1;        // (q=lhi*4+r, d=nf*16+l15)
    #pragma unroll
    for (int r=0; r<4; r++){
      float rinv = 1.f/__shfl(sum, lhi*4+r);   // sum lives at lane l15=q
      size_t base = (size_t)(b*NRES + q0t + lhi*4 + r)*128 + h*32;
      float g0 = b2f(gbuf[base + l15]);
      float g1 = b2f(gbuf[base + 16 + l15]);
      qwg[base + l15]      = f2b(o0[r]*rinv*g0);
      qwg[base + 16 + l15] = f2b(o1[r]*rinv*g1);
    }
  }
}

// ---------------- kernel 3: output projection ----------------
__global__ __launch_bounds__(256) void k_outproj(
    const u16* __restrict__ wg, const u16* __restrict__ wts,
    const float* __restrict__ ob, float* __restrict__ out){
  int tid = threadIdx.x;
  int p0 = blockIdx.x*128;
  int wv = tid>>6, lane = tid&63, l15 = lane&15, lhi = lane>>4;
  const v4f z4 = {0.f,0.f,0.f,0.f};
  v4f acc[8][2];
  #pragma unroll
  for (int mf=0;mf<8;mf++){ acc[mf][0]=z4; acc[mf][1]=z4; }
  const u16* wo = wts + 4*16384;
  #pragma unroll
  for (int ks=0;ks<4;ks++){
    v8s af[8];
    #pragma unroll
    for (int mf=0;mf<8;mf++)
      af[mf] = *(const v8s*)(wg + (size_t)(p0+mf*16+l15)*128 + ks*32 + lhi*8);
    v8s bf[2];
    #pragma unroll
    for (int nf=0;nf<2;nf++)
      bf[nf] = *(const v8s*)(wo + (wv*32+nf*16+l15)*128 + ks*32 + lhi*8);
    #pragma unroll
    for (int mf=0;mf<8;mf++){
      acc[mf][0] = __builtin_amdgcn_mfma_f32_16x16x32_bf16(af[mf], bf[0], acc[mf][0],0,0,0);
      acc[mf][1] = __builtin_amdgcn_mfma_f32_16x16x32_bf16(af[mf], bf[1], acc[mf][1],0,0,0);
    }
  }
  #pragma unroll
  for (int nf=0;nf<2;nf++){
    int n = wv*32 + nf*16 + l15;
    float obn = ob[n];
    #pragma unroll
    for (int mf=0;mf<8;mf++)
      #pragma unroll
      for (int r=0;r<4;r++)
        out[(size_t)(p0+mf*16+lhi*4+r)*128 + n] = acc[mf][nf][r] + obn;
  }
}

extern "C" void kernel_launch(void* const* d_in, const int* in_sizes, int n_in,
                              void* d_out, int out_size, void* d_ws, size_t ws_size,
                              hipStream_t stream){
  const float* pair_act = (const float*)d_in[0];
  const float* pair_mask= (const float*)d_in[1];
  const float* ln_scale = (const float*)d_in[2];
  const float* ln_bias  = (const float*)d_in[3];
  const float* f2w      = (const float*)d_in[4];
  const float* q_w      = (const float*)d_in[5];
  const float* k_w      = (const float*)d_in[6];
  const float* v_w      = (const float*)d_in[7];
  const float* g_w      = (const float*)d_in[8];
  const float* g_b      = (const float*)d_in[9];
  const float* o_w      = (const float*)d_in[10];
  const float* o_b      = (const float*)d_in[11];
  float* out = (float*)d_out;

  u16* qbuf = (u16*)d_ws;                 // q, later weighted*gate
  u16* kbuf = qbuf + (size_t)QKVE;
  u16* vT   = kbuf + (size_t)QKVE;        // [b][h][d][j]
  u16* gbuf = vT   + (size_t)QKVE;        // sigmoid(gate)
  u16* nbb  = gbuf + (size_t)QKVE;        // [h][k/4][q][k%4] bf16 packed
  u16* wts  = nbb  + (size_t)(4*NN);      // 5 x 128x128 bf16

  hipLaunchKernelGGL(k_prep_w, dim3(320), dim3(256), 0, stream,
                     q_w, k_w, v_w, g_w, o_w, wts);
  hipLaunchKernelGGL(k_ln_proj, dim3(1152), dim3(256), 0, stream,
                     pair_act, ln_scale, ln_bias, f2w, g_b, wts,
                     qbuf, kbuf, vT, gbuf, nbb);
  hipLaunchKernelGGL(k_attn, dim3(1536), dim3(256), 0, stream,
                     qbuf, kbuf, vT, gbuf, nbb, pair_mask);
  hipLaunchKernelGGL(k_outproj, dim3(1152), dim3(256), 0, stream,
                     qbuf, wts, o_b, out);
}